// Round 26
// baseline (99.816 us; speedup 1.0000x reference)
//
#include <hip/hip_runtime.h>
#include <math.h>

#define N_DIM 64
#define C_DIM 512
#define K_DIM 64
#define P_DIM 900
#define P_PAD 928          // 29 * 32 (agg K-steps of 32)
#define PTILES 15          // assign p-blocks of 64

typedef __attribute__((ext_vector_type(8))) short short8;   // 8 bf16 = 4 VGPR
typedef __attribute__((ext_vector_type(4))) float f32x4;    // MFMA C/D + x loads
typedef __attribute__((ext_vector_type(4))) uint  u32x4;

#define A2_ELEMS   ((size_t)N_DIM * K_DIM * P_PAD)
#define ASUM_ELEMS ((size_t)N_DIM * K_DIM * PTILES)
#define X_TOTAL    ((size_t)N_DIM * C_DIM * P_DIM)   // 29,491,200 floats

// fp32 -> bf16 bits, round-to-nearest-even (inputs finite)
__device__ inline ushort f2bf(float f) {
  uint u = __builtin_bit_cast(uint, f);
  u += 0x7FFFu + ((u >> 16) & 1u);
  return (ushort)(u >> 16);
}
__device__ inline uint pk2(float a, float b) {
  return (uint)f2bf(a) | ((uint)f2bf(b) << 16);
}

// async global->LDS DMA, 16B per lane; LDS dest = wave-uniform base + lane*16
__device__ __forceinline__ void gload16(const float* g, float* lds_base) {
  __builtin_amdgcn_global_load_lds(
      (const __attribute__((address_space(1))) void*)g,
      (__attribute__((address_space(3))) void*)lds_base, 16, 0, 0);
}

// ---------------------------------------------------------------------------
// Kernel 0: TOUCH -- pure streaming read of x to warm the 256 MB L3
// (x = 110 MB fits). m13-shaped: grid-stride float4, no LDS, no barriers,
// 2048 blocks. Checksum written per-wave to scratch to prevent DCE.
// Separates the cold-HBM read (streaming rate) from the compute kernels,
// which then run in the L3-hot regime (agg's proven-fast regime).
// ---------------------------------------------------------------------------
__global__ __launch_bounds__(256) void touch_x(
    const float* __restrict__ x, float* __restrict__ scratch)
{
  size_t idx = ((size_t)blockIdx.x * 256 + threadIdx.x) * 4;
  const size_t stride = (size_t)gridDim.x * 256 * 4;
  float acc = 0.f;
  for (; idx < X_TOTAL; idx += stride) {        // X_TOTAL divisible by 4
    f32x4 v = *(const f32x4*)(x + idx);
    acc += v[0] + v[1] + v[2] + v[3];
  }
  acc += __shfl_xor(acc, 1);  acc += __shfl_xor(acc, 2);
  acc += __shfl_xor(acc, 4);  acc += __shfl_xor(acc, 8);
  acc += __shfl_xor(acc, 16); acc += __shfl_xor(acc, 32);
  if ((threadIdx.x & 63) == 0)
    scratch[blockIdx.x * 4 + (threadIdx.x >> 6)] = acc;
}

// ---------------------------------------------------------------------------
// Kernel A (r18-proven v10): logits GEMM via MFMA + fused L2-norm + softmax.
// T4 counted-vmcnt pipeline: raw s_barrier + vmcnt(8) keeps the 8 prefetch
// loads/wave in flight across barrier+compute. Chunks 128c x 64p = 32 KB,
// double-buffered. Now runs against L3-HOT x (touch_x prewarmed).
// ks loops fully unrolled (rule #20: runtime-indexed wfrag -> scratch).
// ---------------------------------------------------------------------------
__global__ __launch_bounds__(256, 2) void netvlad_assign(
    const float* __restrict__ x, const float* __restrict__ w,
    ushort* __restrict__ a2, float* __restrict__ asum_part)
{
  const int n = blockIdx.y, bpt = blockIdx.x, p0 = bpt * 64;
  const int tid = threadIdx.x, wv = tid >> 6, lane = tid & 63;
  const int l15 = lane & 15, lhi = lane >> 4;

  __shared__ float xs[2][8192];       // 2 x 32 KB chunk buffers [128 c][64 p]
  __shared__ float wredm[4][4][16];
  __shared__ float wreds[4][4][16];

  // ---- W fragment preload (fp32 -> bf16 regs), k-slot = ks*32 + lhi*8 + j
  short8 wfrag[16];
  const float* wrow = w + (size_t)(wv * 16 + l15) * C_DIM + lhi * 8;
#pragma unroll
  for (int ks = 0; ks < 16; ++ks) {
    f32x4 f0 = *(const f32x4*)(wrow + ks * 32);
    f32x4 f1 = *(const f32x4*)(wrow + ks * 32 + 4);
    u32x4 up;
    up[0] = pk2(f0[0], f0[1]); up[1] = pk2(f0[2], f0[3]);
    up[2] = pk2(f1[0], f1[1]); up[3] = pk2(f1[2], f1[3]);
    wfrag[ks] = __builtin_bit_cast(short8, up);
  }

  // ---- staging geometry: seg = 4 c-rows x 64 p = 1 KB per gload16
  const float* xb = x + (size_t)n * C_DIM * P_DIM;
  int pld = p0 + (lane & 15) * 4;
  if (pld > P_DIM - 4) pld = P_DIM - 4;   // clamp (dup pixels, gated later)
  const int rquad = lane >> 4;            // row-within-segment (0..3)

  // stage chunk ch (128 c-rows) into buffer b: 32 segments, wave wv does 8
#define STAGE(b, ch)                                                           \
  {                                                                            \
    _Pragma("unroll")                                                          \
    for (int i = 0; i < 8; ++i) {                                              \
      int seg = wv + 4 * i;                                                    \
      int rr  = (ch) * 128 + seg * 4 + rquad;                                  \
      gload16(xb + (size_t)rr * P_DIM + pld, &xs[b][seg * 256]);               \
    }                                                                          \
  }

  f32x4 acc[4];
#pragma unroll
  for (int pt = 0; pt < 4; ++pt) acc[pt] = (f32x4){0.f, 0.f, 0.f, 0.f};
  float ssqp[4] = {0.f, 0.f, 0.f, 0.f};

  STAGE(0, 0);
#pragma unroll
  for (int ch = 0; ch < 4; ++ch) {
    if (ch + 1 < 4) STAGE((ch + 1) & 1, ch + 1);
    // counted wait: only the current chunk's 8 loads/wave must land;
    // the 8 prefetch loads stay in flight across barrier + compute (T4).
    if (ch < 3) asm volatile("s_waitcnt vmcnt(8)" ::: "memory");
    else        asm volatile("s_waitcnt vmcnt(0)" ::: "memory");
    __builtin_amdgcn_sched_barrier(0);
    __builtin_amdgcn_s_barrier();       // raw barrier: no vmcnt(0) drain
    const float* buf = xs[ch & 1];
#pragma unroll
    for (int ks = 0; ks < 4; ++ks) {
      f32x4 rd[8];
#pragma unroll
      for (int j = 0; j < 8; ++j)
        rd[j] = *(const f32x4*)&buf[(ks * 32 + 8 * lhi + j) * 64 + l15 * 4];
#pragma unroll
      for (int pt = 0; pt < 4; ++pt) {
        ssqp[pt] += rd[0][pt] * rd[0][pt] + rd[1][pt] * rd[1][pt]
                  + rd[2][pt] * rd[2][pt] + rd[3][pt] * rd[3][pt]
                  + rd[4][pt] * rd[4][pt] + rd[5][pt] * rd[5][pt]
                  + rd[6][pt] * rd[6][pt] + rd[7][pt] * rd[7][pt];
        u32x4 up;
        up[0] = pk2(rd[0][pt], rd[1][pt]); up[1] = pk2(rd[2][pt], rd[3][pt]);
        up[2] = pk2(rd[4][pt], rd[5][pt]); up[3] = pk2(rd[6][pt], rd[7][pt]);
        short8 xf = __builtin_bit_cast(short8, up);
        acc[pt] = __builtin_amdgcn_mfma_f32_16x16x32_bf16(
                      wfrag[ch * 4 + ks], xf, acc[pt], 0, 0, 0);
      }
    }
    __builtin_amdgcn_s_barrier();       // all reads done before buf reuse
  }
#undef STAGE

  // ---- invn per pixel: full ssq = sum over the 4 lhi octet-groups
  float linv[4];
#pragma unroll
  for (int pt = 0; pt < 4; ++pt) {
    float s = ssqp[pt];
    s += __shfl_xor(s, 16);
    s += __shfl_xor(s, 32);
    linv[pt] = 1.0f / fmaxf(sqrtf(s), 1e-12f);
  }

  // ---- softmax over k (64 values per pixel slot, cross-wave via LDS)
  float lg[4][4];
#pragma unroll
  for (int pt = 0; pt < 4; ++pt) {
    float m = -1e30f;
#pragma unroll
    for (int r = 0; r < 4; ++r) { lg[pt][r] = acc[pt][r] * linv[pt]; m = fmaxf(m, lg[pt][r]); }
    m = fmaxf(m, __shfl_xor(m, 16));
    m = fmaxf(m, __shfl_xor(m, 32));
    if (lhi == 0) wredm[wv][pt][l15] = m;
  }
  __syncthreads();
#pragma unroll
  for (int pt = 0; pt < 4; ++pt) {
    float m = fmaxf(fmaxf(wredm[0][pt][l15], wredm[1][pt][l15]),
                    fmaxf(wredm[2][pt][l15], wredm[3][pt][l15]));
    float s = 0.f;
#pragma unroll
    for (int r = 0; r < 4; ++r) { lg[pt][r] = __expf(lg[pt][r] - m); s += lg[pt][r]; }
    s += __shfl_xor(s, 16);
    s += __shfl_xor(s, 32);
    if (lhi == 0) wreds[wv][pt][l15] = s;
  }
  __syncthreads();

  ushort* a2b = a2 + (size_t)n * K_DIM * P_PAD;
  float asr[4] = {0.f, 0.f, 0.f, 0.f};
#pragma unroll
  for (int pt = 0; pt < 4; ++pt) {
    float stot = wreds[0][pt][l15] + wreds[1][pt][l15] +
                 wreds[2][pt][l15] + wreds[3][pt][l15];
    float rs = 1.0f / stot;
    int p = p0 + 4 * l15 + pt;          // vector-load pixel mapping
    bool vv = p < P_DIM;
#pragma unroll
    for (int r = 0; r < 4; ++r) {
      float a = lg[pt][r] * rs;
      if (vv) asr[r] += a;
      if (p < P_PAD) {
        int k = wv * 16 + lhi * 4 + r;
        a2b[(size_t)k * P_PAD + p] = vv ? f2bf(a * linv[pt]) : (ushort)0;
      }
    }
  }
#pragma unroll
  for (int r = 0; r < 4; ++r) {
    float v = asr[r];
    v += __shfl_xor(v, 1); v += __shfl_xor(v, 2);
    v += __shfl_xor(v, 4); v += __shfl_xor(v, 8);
    if (l15 == 0) {
      int k = wv * 16 + lhi * 4 + r;
      asum_part[((size_t)n * K_DIM + k) * PTILES + bpt] = v;
    }
  }
}

// ---------------------------------------------------------------------------
// Kernel B: agg[n,k,c] = sum_p a2[k,p]*x[c,p] via MFMA (x L3-hot).
// Fused epilogue: out = acc - asum*centroid.
// ---------------------------------------------------------------------------
__global__ __launch_bounds__(256, 4) void netvlad_agg(
    const float* __restrict__ x, const ushort* __restrict__ a2,
    const float* __restrict__ asum_part, const float* __restrict__ cent,
    float* __restrict__ out)
{
  const int n = blockIdx.y, ct = blockIdx.x, c0 = ct * 64;
  const int tid = threadIdx.x, wave = tid >> 6, lane = tid & 63;
  const int l15 = lane & 15, lhi = lane >> 4;

  __shared__ float asum_s[64];
  if (tid < 64) {
    const float* ap = asum_part + ((size_t)n * K_DIM + tid) * PTILES;
    float s = 0.f;
#pragma unroll
    for (int j = 0; j < PTILES; ++j) s += ap[j];
    asum_s[tid] = s;
  }
  __syncthreads();

  f32x4 acc[4];
#pragma unroll
  for (int mt = 0; mt < 4; ++mt) acc[mt] = (f32x4){0.f, 0.f, 0.f, 0.f};

  const float*  xrow = x + (size_t)n * C_DIM * P_DIM
                         + (size_t)(c0 + wave * 16 + l15) * P_DIM;
  const ushort* ab   = a2 + (size_t)n * K_DIM * P_PAD;

  for (int ks = 0; ks < 29; ++ks) {
    int pb = ks * 32 + lhi * 8;
    short8 bfrag;
    if (pb + 8 <= P_DIM) {
      f32x4 f0 = *(const f32x4*)(xrow + pb);
      f32x4 f1 = *(const f32x4*)(xrow + pb + 4);
      u32x4 up;
      up[0] = pk2(f0[0], f0[1]); up[1] = pk2(f0[2], f0[3]);
      up[2] = pk2(f1[0], f1[1]); up[3] = pk2(f1[2], f1[3]);
      bfrag = __builtin_bit_cast(short8, up);
    } else {
#pragma unroll
      for (int j = 0; j < 8; ++j)
        bfrag[j] = (pb + j < P_DIM) ? (short)f2bf(xrow[pb + j]) : (short)0;
    }
#pragma unroll
    for (int mt = 0; mt < 4; ++mt) {
      short8 afrag = *(const short8*)(ab + (size_t)(mt * 16 + l15) * P_PAD
                                         + ks * 32 + lhi * 8);
      acc[mt] = __builtin_amdgcn_mfma_f32_16x16x32_bf16(afrag, bfrag, acc[mt], 0, 0, 0);
    }
  }

  const int c = c0 + wave * 16 + l15;
#pragma unroll
  for (int mt = 0; mt < 4; ++mt) {
#pragma unroll
    for (int r = 0; r < 4; ++r) {
      int k = mt * 16 + lhi * 4 + r;
      out[((size_t)n * K_DIM + k) * C_DIM + c] =
          acc[mt][r] - asum_s[k] * cent[(size_t)k * C_DIM + c];
    }
  }
}

extern "C" void kernel_launch(void* const* d_in, const int* in_sizes, int n_in,
                              void* d_out, int out_size, void* d_ws, size_t ws_size,
                              hipStream_t stream) {
  const float* x    = (const float*)d_in[0];
  const float* w    = (const float*)d_in[1];
  const float* cent = (const float*)d_in[2];
  float* out = (float*)d_out;

  ushort* a2        = (ushort*)d_ws;
  float*  asum_part = (float*)((char*)d_ws + A2_ELEMS * sizeof(ushort));
  float*  scratch   = asum_part + ASUM_ELEMS;   // touch checksums (8192 f)

  touch_x       <<<2048, 256, 0, stream>>>(x, scratch);
  netvlad_assign<<<dim3(PTILES, N_DIM), 256, 0, stream>>>(x, w, a2, asum_part);
  netvlad_agg   <<<dim3(8, N_DIM),      256, 0, stream>>>(x, a2, asum_part, cent, out);
}

// Round 27
// 93.443 us; speedup vs baseline: 1.0682x; 1.0682x over previous
//
#include <hip/hip_runtime.h>
#include <math.h>

#define N_DIM 64
#define C_DIM 512
#define K_DIM 64
#define P_DIM 900
#define P_PAD 928          // a2 padded pixels (29*32)
#define PTILES 15          // 64-px tiles
#define PXR 960            // xtf px rounding (15*64)

typedef __attribute__((ext_vector_type(8))) short short8;   // 8 bf16 = 4 VGPR
typedef __attribute__((ext_vector_type(4))) float f32x4;
typedef __attribute__((ext_vector_type(4))) uint  u32x4;

#define A2_ELEMS   ((size_t)N_DIM * K_DIM * P_PAD)
#define ASUM_ELEMS ((size_t)N_DIM * K_DIM * PTILES)

// fp32 -> bf16 bits, round-to-nearest-even (inputs finite)
__device__ inline ushort f2bf(float f) {
  uint u = __builtin_bit_cast(uint, f);
  u += 0x7FFFu + ((u >> 16) & 1u);
  return (ushort)(u >> 16);
}
__device__ inline uint pk2(float a, float b) {
  return (uint)f2bf(a) | ((uint)f2bf(b) << 16);
}

// ---------------------------------------------------------------------------
// Kernel T (v5): PURE-COPY-SHAPED transpose. Evidence chain: touch (r26)
// streams cold reads at 4+ TB/s; fillBuffer writes at 7 TB/s; r24/25
// transpose stuck at 3.3 TB/s -- its defect was 15 scattered 1KB panel
// writes per block. v5 layout xtf[n][oct][960 px][8 c]: block (n,oct) reads
// 28.8 KB contiguous AND writes its 15,360B panel contiguously (4KB/pass).
// Both sides now linear streams. One barrier. px>=900 zero-padded.
// ---------------------------------------------------------------------------
__global__ __launch_bounds__(256, 4) void transpose_x(
    const float* __restrict__ x, ushort* __restrict__ xtf)
{
  const int oct = blockIdx.x, n = blockIdx.y;
  const int tid = threadIdx.x;
  __shared__ float lds[8][1024];

  const float* xb = x + ((size_t)n * C_DIM + oct * 8) * P_DIM;

  // stage: thread covers 8 float4 (flat = i*256+tid -> row r, px pos)
  f32x4 v[8];
#pragma unroll
  for (int i = 0; i < 8; ++i) {
    int flat = i * 256 + tid;
    int r = flat >> 8;
    int pos = (flat & 255) * 4;
    int pos2 = pos > 896 ? 896 : pos;    // rows are 900 px; dup-clamp tail
    v[i] = *(const f32x4*)(xb + (size_t)r * P_DIM + pos2);
  }
#pragma unroll
  for (int i = 0; i < 8; ++i) {
    int flat = i * 256 + tid;
    int r = flat >> 8;
    int pos = (flat & 255) * 4;
    *(f32x4*)&lds[r][pos] = v[i];
  }
  __syncthreads();

  // write: fully contiguous 15,360B panel (4KB per pass, last pass 3KB)
  ushort* dst = xtf + ((size_t)(n * 64 + oct) * PXR) * 8;
#pragma unroll
  for (int j = 0; j < 4; ++j) {
    int px = j * 256 + tid;              // 0..1023
    if (px < PXR) {
      float vv[8];
#pragma unroll
      for (int c = 0; c < 8; ++c) vv[c] = (px < P_DIM) ? lds[c][px] : 0.f;
      u32x4 wvr;
      wvr[0] = pk2(vv[0], vv[1]); wvr[1] = pk2(vv[2], vv[3]);
      wvr[2] = pk2(vv[4], vv[5]); wvr[3] = pk2(vv[6], vv[7]);
      *(u32x4*)(dst + (size_t)px * 8) = wvr;
    }
  }
}

// ---------------------------------------------------------------------------
// Kernel A (v14): logits GEMM from xtf [n][oct][960][8c] + softmax.
// Structure-bound 67us LDS-staging assign replaced by the proven direct-
// fragment form (r24: ~12us): inner loop = short8 load + MFMA + in-loop
// bf16 ssq. No LDS staging, no barriers in the GEMM. invn via shfl_xor.
// ks loop fully unrolled (rule #20: wfrag runtime index -> scratch).
// ---------------------------------------------------------------------------
__global__ __launch_bounds__(256, 2) void netvlad_assign(
    const float* __restrict__ w, const ushort* __restrict__ xtf,
    ushort* __restrict__ a2, float* __restrict__ asum_part)
{
  const int n = blockIdx.y, bpt = blockIdx.x, p0 = bpt * 64;
  const int tid = threadIdx.x, wave = tid >> 6, lane = tid & 63;
  const int l15 = lane & 15, lhi = lane >> 4;

  __shared__ float wredm[4][4][16];
  __shared__ float wreds[4][4][16];

  short8 wfrag[16];
  const float* wrow = w + (size_t)(wave * 16 + l15) * C_DIM + lhi * 8;
#pragma unroll
  for (int ks = 0; ks < 16; ++ks) {
    f32x4 f0 = *(const f32x4*)(wrow + ks * 32);
    f32x4 f1 = *(const f32x4*)(wrow + ks * 32 + 4);
    u32x4 up;
    up[0] = pk2(f0[0], f0[1]); up[1] = pk2(f0[2], f0[3]);
    up[2] = pk2(f1[0], f1[1]); up[3] = pk2(f1[2], f1[3]);
    wfrag[ks] = __builtin_bit_cast(short8, up);
  }

  const ushort* xf_base = xtf + ((size_t)n * 64 * PXR) * 8;
  f32x4 acc[4];
#pragma unroll
  for (int pt = 0; pt < 4; ++pt) acc[pt] = (f32x4){0.f, 0.f, 0.f, 0.f};
  float ssqp[4] = {0.f, 0.f, 0.f, 0.f};

#pragma unroll
  for (int ks = 0; ks < 16; ++ks) {
#pragma unroll
    for (int pt = 0; pt < 4; ++pt) {
      short8 xf = *(const short8*)(xf_base
                    + ((size_t)(ks * 4 + lhi) * PXR + p0 + pt * 16 + l15) * 8);
      u32x4 uw = __builtin_bit_cast(u32x4, xf);
#pragma unroll
      for (int wd = 0; wd < 4; ++wd) {
        float lo = __builtin_bit_cast(float, uw[wd] << 16);
        float hi = __builtin_bit_cast(float, uw[wd] & 0xffff0000u);
        ssqp[pt] += lo * lo + hi * hi;
      }
      acc[pt] = __builtin_amdgcn_mfma_f32_16x16x32_bf16(wfrag[ks], xf, acc[pt], 0, 0, 0);
    }
  }

  // invn per pixel: lane holds 128 of 512 c -> reduce over lhi octet-groups
  float linv[4];
#pragma unroll
  for (int pt = 0; pt < 4; ++pt) {
    float s = ssqp[pt];
    s += __shfl_xor(s, 16);
    s += __shfl_xor(s, 32);
    linv[pt] = 1.0f / fmaxf(sqrtf(s), 1e-12f);
  }

  float lg[4][4];
#pragma unroll
  for (int pt = 0; pt < 4; ++pt) {
    float m = -1e30f;
#pragma unroll
    for (int r = 0; r < 4; ++r) { lg[pt][r] = acc[pt][r] * linv[pt]; m = fmaxf(m, lg[pt][r]); }
    m = fmaxf(m, __shfl_xor(m, 16));
    m = fmaxf(m, __shfl_xor(m, 32));
    if (lhi == 0) wredm[wave][pt][l15] = m;
  }
  __syncthreads();
#pragma unroll
  for (int pt = 0; pt < 4; ++pt) {
    float m = fmaxf(fmaxf(wredm[0][pt][l15], wredm[1][pt][l15]),
                    fmaxf(wredm[2][pt][l15], wredm[3][pt][l15]));
    float s = 0.f;
#pragma unroll
    for (int r = 0; r < 4; ++r) { lg[pt][r] = __expf(lg[pt][r] - m); s += lg[pt][r]; }
    s += __shfl_xor(s, 16);
    s += __shfl_xor(s, 32);
    if (lhi == 0) wreds[wave][pt][l15] = s;
  }
  __syncthreads();

  ushort* a2b = a2 + (size_t)n * K_DIM * P_PAD;
  float asr[4] = {0.f, 0.f, 0.f, 0.f};
#pragma unroll
  for (int pt = 0; pt < 4; ++pt) {
    float stot = wreds[0][pt][l15] + wreds[1][pt][l15] +
                 wreds[2][pt][l15] + wreds[3][pt][l15];
    float rs = 1.0f / stot;
    int p = p0 + pt * 16 + l15;
    bool vv = p < P_DIM;
#pragma unroll
    for (int r = 0; r < 4; ++r) {
      float a = lg[pt][r] * rs;
      if (vv) asr[r] += a;
      if (p < P_PAD) {
        int k = wave * 16 + lhi * 4 + r;
        a2b[(size_t)k * P_PAD + p] = vv ? f2bf(a * linv[pt]) : (ushort)0;
      }
    }
  }
#pragma unroll
  for (int r = 0; r < 4; ++r) {
    float v = asr[r];
    v += __shfl_xor(v, 1); v += __shfl_xor(v, 2);
    v += __shfl_xor(v, 4); v += __shfl_xor(v, 8);
    if (l15 == 0) {
      int k = wave * 16 + lhi * 4 + r;
      asum_part[((size_t)n * K_DIM + k) * PTILES + bpt] = v;
    }
  }
}

// ---------------------------------------------------------------------------
// Kernel B: agg[n,k,c] = sum_p a2[k,p]*x[c,p] via MFMA (x L3-hot after T).
// Fused epilogue: out = acc - asum*centroid.
// ---------------------------------------------------------------------------
__global__ __launch_bounds__(256, 4) void netvlad_agg(
    const float* __restrict__ x, const ushort* __restrict__ a2,
    const float* __restrict__ asum_part, const float* __restrict__ cent,
    float* __restrict__ out)
{
  const int n = blockIdx.y, ct = blockIdx.x, c0 = ct * 64;
  const int tid = threadIdx.x, wave = tid >> 6, lane = tid & 63;
  const int l15 = lane & 15, lhi = lane >> 4;

  __shared__ float asum_s[64];
  if (tid < 64) {
    const float* ap = asum_part + ((size_t)n * K_DIM + tid) * PTILES;
    float s = 0.f;
#pragma unroll
    for (int j = 0; j < PTILES; ++j) s += ap[j];
    asum_s[tid] = s;
  }
  __syncthreads();

  f32x4 acc[4];
#pragma unroll
  for (int mt = 0; mt < 4; ++mt) acc[mt] = (f32x4){0.f, 0.f, 0.f, 0.f};

  const float*  xrow = x + (size_t)n * C_DIM * P_DIM
                         + (size_t)(c0 + wave * 16 + l15) * P_DIM;
  const ushort* ab   = a2 + (size_t)n * K_DIM * P_PAD;

  for (int ks = 0; ks < 29; ++ks) {
    int pb = ks * 32 + lhi * 8;
    short8 bfrag;
    if (pb + 8 <= P_DIM) {
      f32x4 f0 = *(const f32x4*)(xrow + pb);
      f32x4 f1 = *(const f32x4*)(xrow + pb + 4);
      u32x4 up;
      up[0] = pk2(f0[0], f0[1]); up[1] = pk2(f0[2], f0[3]);
      up[2] = pk2(f1[0], f1[1]); up[3] = pk2(f1[2], f1[3]);
      bfrag = __builtin_bit_cast(short8, up);
    } else {
#pragma unroll
      for (int j = 0; j < 8; ++j)
        bfrag[j] = (pb + j < P_DIM) ? (short)f2bf(xrow[pb + j]) : (short)0;
    }
#pragma unroll
    for (int mt = 0; mt < 4; ++mt) {
      short8 afrag = *(const short8*)(ab + (size_t)(mt * 16 + l15) * P_PAD
                                         + ks * 32 + lhi * 8);
      acc[mt] = __builtin_amdgcn_mfma_f32_16x16x32_bf16(afrag, bfrag, acc[mt], 0, 0, 0);
    }
  }

  const int c = c0 + wave * 16 + l15;
#pragma unroll
  for (int mt = 0; mt < 4; ++mt) {
#pragma unroll
    for (int r = 0; r < 4; ++r) {
      int k = mt * 16 + lhi * 4 + r;
      out[((size_t)n * K_DIM + k) * C_DIM + c] =
          acc[mt][r] - asum_s[k] * cent[(size_t)k * C_DIM + c];
    }
  }
}

extern "C" void kernel_launch(void* const* d_in, const int* in_sizes, int n_in,
                              void* d_out, int out_size, void* d_ws, size_t ws_size,
                              hipStream_t stream) {
  const float* x    = (const float*)d_in[0];
  const float* w    = (const float*)d_in[1];
  const float* cent = (const float*)d_in[2];
  float* out = (float*)d_out;

  char* wsb = (char*)d_ws;
  ushort* a2        = (ushort*)wsb;
  float*  asum_part = (float*)(wsb + A2_ELEMS * sizeof(ushort));
  ushort* xtf       = (ushort*)((char*)(asum_part + ASUM_ELEMS));

  transpose_x   <<<dim3(64, N_DIM),     256, 0, stream>>>(x, xtf);
  netvlad_assign<<<dim3(PTILES, N_DIM), 256, 0, stream>>>(w, xtf, a2, asum_part);
  netvlad_agg   <<<dim3(8, N_DIM),      256, 0, stream>>>(x, a2, asum_part, cent, out);
}

// Round 28
// 77.676 us; speedup vs baseline: 1.2850x; 1.2030x over previous
//
#include <hip/hip_runtime.h>
#include <math.h>

#define N_DIM 64
#define C_DIM 512
#define K_DIM 64
#define P_DIM 900
#define P_PAD 928          // 29 * 32 (agg K-steps of 32)
#define PTILES 15          // assign p-blocks of 64

typedef __attribute__((ext_vector_type(8))) short short8;   // 8 bf16 = 4 VGPR
typedef __attribute__((ext_vector_type(4))) float f32x4;    // MFMA C/D + x loads
typedef __attribute__((ext_vector_type(4))) uint  u32x4;

#define A2_ELEMS   ((size_t)N_DIM * K_DIM * P_PAD)

// fp32 -> bf16 bits, round-to-nearest-even (inputs finite)
__device__ inline ushort f2bf(float f) {
  uint u = __builtin_bit_cast(uint, f);
  u += 0x7FFFu + ((u >> 16) & 1u);
  return (ushort)(u >> 16);
}
__device__ inline uint pk2(float a, float b) {
  return (uint)f2bf(a) | ((uint)f2bf(b) << 16);
}

// async global->LDS DMA, 16B per lane; LDS dest = wave-uniform base + lane*16
__device__ __forceinline__ void gload16(const float* g, float* lds_base) {
  __builtin_amdgcn_global_load_lds(
      (const __attribute__((address_space(1))) void*)g,
      (__attribute__((address_space(3))) void*)lds_base, 16, 0, 0);
}

// ---------------------------------------------------------------------------
// Kernel A (v10 + T1): r18-proven counted-vmcnt kernel, UNCHANGED body,
// plus a bijective XCD-aware block swizzle. Diagnosis (r27 ledger): each
// block reads 256B column-slices of 512 rows; sibling ptile-blocks of one
// image jointly cover full 3600B rows but round-robin dispatch puts them on
// DIFFERENT XCDs (private L2s) -> every XCD re-fetches rows in 256B shreds
// -> 1.3 TB/s. Swizzle: all 15 ptiles of image n on XCD n%8, adjacent
// slots -> that L2 assembles each row once for 15 consumers (T1; slice
// 1.8 MB << 4 MB L2). Grid 960 = 8 XCDs x 120 slots, bijective.
// ---------------------------------------------------------------------------
__global__ __launch_bounds__(256, 2) void netvlad_assign(
    const float* __restrict__ x, const float* __restrict__ w,
    ushort* __restrict__ a2, float* __restrict__ asum_part)
{
  const int bid  = blockIdx.x;
  const int xcd  = bid & 7;           // dispatch round-robin -> XCD id
  const int slot = bid >> 3;          // 0..119 within XCD
  const int n    = xcd + 8 * (slot / PTILES);
  const int bpt  = slot % PTILES;
  const int p0   = bpt * 64;
  const int tid = threadIdx.x, wv = tid >> 6, lane = tid & 63;
  const int l15 = lane & 15, lhi = lane >> 4;

  __shared__ float xs[2][8192];       // 2 x 32 KB chunk buffers [128 c][64 p]
  __shared__ float wredm[4][4][16];
  __shared__ float wreds[4][4][16];

  // ---- W fragment preload (fp32 -> bf16 regs), k-slot = ks*32 + lhi*8 + j
  short8 wfrag[16];
  const float* wrow = w + (size_t)(wv * 16 + l15) * C_DIM + lhi * 8;
#pragma unroll
  for (int ks = 0; ks < 16; ++ks) {
    f32x4 f0 = *(const f32x4*)(wrow + ks * 32);
    f32x4 f1 = *(const f32x4*)(wrow + ks * 32 + 4);
    u32x4 up;
    up[0] = pk2(f0[0], f0[1]); up[1] = pk2(f0[2], f0[3]);
    up[2] = pk2(f1[0], f1[1]); up[3] = pk2(f1[2], f1[3]);
    wfrag[ks] = __builtin_bit_cast(short8, up);
  }

  // ---- staging geometry: seg = 4 c-rows x 64 p = 1 KB per gload16
  const float* xb = x + (size_t)n * C_DIM * P_DIM;
  int pld = p0 + (lane & 15) * 4;
  if (pld > P_DIM - 4) pld = P_DIM - 4;   // clamp (dup pixels, gated later)
  const int rquad = lane >> 4;            // row-within-segment (0..3)

  // stage chunk ch (128 c-rows) into buffer b: 32 segments, wave wv does 8
#define STAGE(b, ch)                                                           \
  {                                                                            \
    _Pragma("unroll")                                                          \
    for (int i = 0; i < 8; ++i) {                                              \
      int seg = wv + 4 * i;                                                    \
      int rr  = (ch) * 128 + seg * 4 + rquad;                                  \
      gload16(xb + (size_t)rr * P_DIM + pld, &xs[b][seg * 256]);               \
    }                                                                          \
  }

  f32x4 acc[4];
#pragma unroll
  for (int pt = 0; pt < 4; ++pt) acc[pt] = (f32x4){0.f, 0.f, 0.f, 0.f};
  float ssqp[4] = {0.f, 0.f, 0.f, 0.f};

  STAGE(0, 0);
#pragma unroll
  for (int ch = 0; ch < 4; ++ch) {
    if (ch + 1 < 4) STAGE((ch + 1) & 1, ch + 1);
    // counted wait: only the current chunk's 8 loads/wave must land;
    // the 8 prefetch loads stay in flight across barrier + compute (T4).
    if (ch < 3) asm volatile("s_waitcnt vmcnt(8)" ::: "memory");
    else        asm volatile("s_waitcnt vmcnt(0)" ::: "memory");
    __builtin_amdgcn_sched_barrier(0);
    __builtin_amdgcn_s_barrier();       // raw barrier: no vmcnt(0) drain
    const float* buf = xs[ch & 1];
#pragma unroll
    for (int ks = 0; ks < 4; ++ks) {
      f32x4 rd[8];
#pragma unroll
      for (int j = 0; j < 8; ++j)
        rd[j] = *(const f32x4*)&buf[(ks * 32 + 8 * lhi + j) * 64 + l15 * 4];
#pragma unroll
      for (int pt = 0; pt < 4; ++pt) {
        ssqp[pt] += rd[0][pt] * rd[0][pt] + rd[1][pt] * rd[1][pt]
                  + rd[2][pt] * rd[2][pt] + rd[3][pt] * rd[3][pt]
                  + rd[4][pt] * rd[4][pt] + rd[5][pt] * rd[5][pt]
                  + rd[6][pt] * rd[6][pt] + rd[7][pt] * rd[7][pt];
        u32x4 up;
        up[0] = pk2(rd[0][pt], rd[1][pt]); up[1] = pk2(rd[2][pt], rd[3][pt]);
        up[2] = pk2(rd[4][pt], rd[5][pt]); up[3] = pk2(rd[6][pt], rd[7][pt]);
        short8 xf = __builtin_bit_cast(short8, up);
        acc[pt] = __builtin_amdgcn_mfma_f32_16x16x32_bf16(
                      wfrag[ch * 4 + ks], xf, acc[pt], 0, 0, 0);
      }
    }
    __builtin_amdgcn_s_barrier();       // all reads done before buf reuse
  }
#undef STAGE

  // ---- invn per pixel: full ssq = sum over the 4 lhi octet-groups
  float linv[4];
#pragma unroll
  for (int pt = 0; pt < 4; ++pt) {
    float s = ssqp[pt];
    s += __shfl_xor(s, 16);
    s += __shfl_xor(s, 32);
    linv[pt] = 1.0f / fmaxf(sqrtf(s), 1e-12f);
  }

  // ---- softmax over k (64 values per pixel slot, cross-wave via LDS)
  float lg[4][4];
#pragma unroll
  for (int pt = 0; pt < 4; ++pt) {
    float m = -1e30f;
#pragma unroll
    for (int r = 0; r < 4; ++r) { lg[pt][r] = acc[pt][r] * linv[pt]; m = fmaxf(m, lg[pt][r]); }
    m = fmaxf(m, __shfl_xor(m, 16));
    m = fmaxf(m, __shfl_xor(m, 32));
    if (lhi == 0) wredm[wv][pt][l15] = m;
  }
  __syncthreads();
#pragma unroll
  for (int pt = 0; pt < 4; ++pt) {
    float m = fmaxf(fmaxf(wredm[0][pt][l15], wredm[1][pt][l15]),
                    fmaxf(wredm[2][pt][l15], wredm[3][pt][l15]));
    float s = 0.f;
#pragma unroll
    for (int r = 0; r < 4; ++r) { lg[pt][r] = __expf(lg[pt][r] - m); s += lg[pt][r]; }
    s += __shfl_xor(s, 16);
    s += __shfl_xor(s, 32);
    if (lhi == 0) wreds[wv][pt][l15] = s;
  }
  __syncthreads();

  ushort* a2b = a2 + (size_t)n * K_DIM * P_PAD;
  float asr[4] = {0.f, 0.f, 0.f, 0.f};
#pragma unroll
  for (int pt = 0; pt < 4; ++pt) {
    float stot = wreds[0][pt][l15] + wreds[1][pt][l15] +
                 wreds[2][pt][l15] + wreds[3][pt][l15];
    float rs = 1.0f / stot;
    int p = p0 + 4 * l15 + pt;          // vector-load pixel mapping
    bool vv = p < P_DIM;
#pragma unroll
    for (int r = 0; r < 4; ++r) {
      float a = lg[pt][r] * rs;
      if (vv) asr[r] += a;
      if (p < P_PAD) {
        int k = wv * 16 + lhi * 4 + r;
        a2b[(size_t)k * P_PAD + p] = vv ? f2bf(a * linv[pt]) : (ushort)0;
      }
    }
  }
#pragma unroll
  for (int r = 0; r < 4; ++r) {
    float v = asr[r];
    v += __shfl_xor(v, 1); v += __shfl_xor(v, 2);
    v += __shfl_xor(v, 4); v += __shfl_xor(v, 8);
    if (l15 == 0) {
      int k = wv * 16 + lhi * 4 + r;
      asum_part[((size_t)n * K_DIM + k) * PTILES + bpt] = v;
    }
  }
}

// ---------------------------------------------------------------------------
// Kernel B: agg[n,k,c] = sum_p a2[k,p]*x[c,p] via MFMA (x L3-hot after A).
// Fused epilogue: out = acc - asum*centroid.
// ---------------------------------------------------------------------------
__global__ __launch_bounds__(256, 4) void netvlad_agg(
    const float* __restrict__ x, const ushort* __restrict__ a2,
    const float* __restrict__ asum_part, const float* __restrict__ cent,
    float* __restrict__ out)
{
  const int n = blockIdx.y, ct = blockIdx.x, c0 = ct * 64;
  const int tid = threadIdx.x, wave = tid >> 6, lane = tid & 63;
  const int l15 = lane & 15, lhi = lane >> 4;

  __shared__ float asum_s[64];
  if (tid < 64) {
    const float* ap = asum_part + ((size_t)n * K_DIM + tid) * PTILES;
    float s = 0.f;
#pragma unroll
    for (int j = 0; j < PTILES; ++j) s += ap[j];
    asum_s[tid] = s;
  }
  __syncthreads();

  f32x4 acc[4];
#pragma unroll
  for (int mt = 0; mt < 4; ++mt) acc[mt] = (f32x4){0.f, 0.f, 0.f, 0.f};

  const float*  xrow = x + (size_t)n * C_DIM * P_DIM
                         + (size_t)(c0 + wave * 16 + l15) * P_DIM;
  const ushort* ab   = a2 + (size_t)n * K_DIM * P_PAD;

  for (int ks = 0; ks < 29; ++ks) {
    int pb = ks * 32 + lhi * 8;
    short8 bfrag;
    if (pb + 8 <= P_DIM) {
      f32x4 f0 = *(const f32x4*)(xrow + pb);
      f32x4 f1 = *(const f32x4*)(xrow + pb + 4);
      u32x4 up;
      up[0] = pk2(f0[0], f0[1]); up[1] = pk2(f0[2], f0[3]);
      up[2] = pk2(f1[0], f1[1]); up[3] = pk2(f1[2], f1[3]);
      bfrag = __builtin_bit_cast(short8, up);
    } else {
#pragma unroll
      for (int j = 0; j < 8; ++j)
        bfrag[j] = (pb + j < P_DIM) ? (short)f2bf(xrow[pb + j]) : (short)0;
    }
#pragma unroll
    for (int mt = 0; mt < 4; ++mt) {
      short8 afrag = *(const short8*)(ab + (size_t)(mt * 16 + l15) * P_PAD
                                         + ks * 32 + lhi * 8);
      acc[mt] = __builtin_amdgcn_mfma_f32_16x16x32_bf16(afrag, bfrag, acc[mt], 0, 0, 0);
    }
  }

  const int c = c0 + wave * 16 + l15;
#pragma unroll
  for (int mt = 0; mt < 4; ++mt) {
#pragma unroll
    for (int r = 0; r < 4; ++r) {
      int k = mt * 16 + lhi * 4 + r;
      out[((size_t)n * K_DIM + k) * C_DIM + c] =
          acc[mt][r] - asum_s[k] * cent[(size_t)k * C_DIM + c];
    }
  }
}

extern "C" void kernel_launch(void* const* d_in, const int* in_sizes, int n_in,
                              void* d_out, int out_size, void* d_ws, size_t ws_size,
                              hipStream_t stream) {
  const float* x    = (const float*)d_in[0];
  const float* w    = (const float*)d_in[1];
  const float* cent = (const float*)d_in[2];
  float* out = (float*)d_out;

  ushort* a2        = (ushort*)d_ws;
  float*  asum_part = (float*)((char*)d_ws + A2_ELEMS * sizeof(ushort));

  netvlad_assign<<<dim3(PTILES * N_DIM), 256, 0, stream>>>(x, w, a2, asum_part);
  netvlad_agg   <<<dim3(8, N_DIM),       256, 0, stream>>>(x, a2, asum_part, cent, out);
}